// Round 13
// baseline (367.767 us; speedup 1.0000x reference)
//
#include <hip/hip_runtime.h>
#include <hip/hip_bf16.h>

// B=32, C=256, H=36, W=64, n=4096.  P = H*W = 2304.  NCOL = B*C = 8192.
#define P_HW   2304
#define NG     4096
#define NCOL   8192
#define KDIM   P_HW
#define NKT    36          // K-tiles of 64: 2304/64

typedef __bf16 bf16x8 __attribute__((ext_vector_type(8)));
typedef float  f32x4  __attribute__((ext_vector_type(4)));

__device__ __forceinline__ unsigned short f2bf(float f) {
    union { float f; unsigned int u; } x; x.f = f;
    unsigned int r = x.u + 0x7FFFu + ((x.u >> 16) & 1u);   // RNE
    return (unsigned short)(r >> 16);
}

// ---------------------------------------------------------------------------
// Prep: cast + masks (no zero-out; GEMM epilogue stores directly).
// ---------------------------------------------------------------------------
__global__ __launch_bounds__(256) void prep_kernel(
    const float* __restrict__ feat,
    const float* __restrict__ mu,
    const float* __restrict__ logsx,
    const float* __restrict__ logsy,
    const float* __restrict__ rho,
    unsigned short* __restrict__ F,
    unsigned short* __restrict__ G) {
    const int bid = blockIdx.x;
    const int tid = threadIdx.x;
    if (bid < 9216) {
        const size_t i = ((size_t)bid * 256 + tid) * 8;
        const float4 v0 = *(const float4*)(feat + i);
        const float4 v1 = *(const float4*)(feat + i + 4);
        union { unsigned short s[8]; uint4 q; } o;
        o.s[0] = f2bf(v0.x); o.s[1] = f2bf(v0.y); o.s[2] = f2bf(v0.z); o.s[3] = f2bf(v0.w);
        o.s[4] = f2bf(v1.x); o.s[5] = f2bf(v1.y); o.s[6] = f2bf(v1.z); o.s[7] = f2bf(v1.w);
        *(uint4*)(F + i) = o.q;
    } else {
        const int n = bid - 9216;
        const float mux = mu[2 * n], muy = mu[2 * n + 1];
        const float sx = __expf(logsx[n]) + 1e-6f;
        const float sy = __expf(logsy[n]) + 1e-6f;
        const float r  = tanhf(rho[n]);
        const float inv_den = 1.0f / (2.0f * (1.0f - r * r + 1e-6f));
        const float isx = 1.0f / sx, isy = 1.0f / sy;
        for (int base = tid * 8; base < P_HW; base += 2048) {
            const int h = base >> 6, w0 = base & 63;      // W = 64
            const float Y  = -1.0f + (float)h * (2.0f / 35.0f);
            const float yc = (Y - muy) * isy;
            union { unsigned short s[8]; uint4 q; } o;
#pragma unroll
            for (int j = 0; j < 8; ++j) {
                const float X  = -1.0f + (float)(w0 + j) * (2.0f / 63.0f);
                const float xc = (X - mux) * isx;
                const float A  = xc * xc + yc * yc - 2.0f * r * xc * yc;
                o.s[j] = f2bf(__expf(-A * inv_den));
            }
            *(uint4*)&G[(size_t)n * P_HW + base] = o.q;
        }
    }
}

// ---------------------------------------------------------------------------
// GEMM v12: 4 waves (1/SIMD, 512-reg cap), wave tile 128x128 — HALVES the
// LDS-read bytes per FLOP, which R4-R11 showed is co-binding with MFMA.
// R11 post-mortem: 512-thr blocks cap each wave at 256 total regs ->
// acc[8][4] + frags spill in every 8-phase variant (WRITE 21 MB, VGPR 128).
// v12 flips the trade: 256 thr = 4 waves = 1 wave/SIMD, acc 8x8 (256 AGPR)
// + frags ~64 + addr ~30 = ~350 <= 512, NO spill.  LDS reads per CU-K64:
// 64 KB vs v4's 96 KB/K32: per-FLOP read bytes halve; budget MFMA 2483 ||
// LDS 2259 || L2 1170 cy per K64.  MFMA queue depth (128 independent
// MFMAs/tile) gives single-wave ILP; staging for t+1 issues at tile START
// (~2500 cy lead) so end-of-tile vmcnt(0) is cheap.  BK=64 row = 128 B ->
// proven chunk^(r&7) swizzle (0 conflicts).  Free-run v4-style: ONE
// vmcnt(0)+barrier per tile, x2 unroll static bases.
// ---------------------------------------------------------------------------
__device__ __forceinline__ void async16(const void* g, void* l) {
    __builtin_amdgcn_global_load_lds(
        (__attribute__((address_space(1))) void*)(unsigned long long)g,
        (__attribute__((address_space(3))) void*)(unsigned int)(unsigned long long)l,
        16, 0, 0);
}

__global__ __launch_bounds__(256, 1) void gemm_fused(
    const unsigned short* __restrict__ G,   // [NG][K] bf16
    const unsigned short* __restrict__ F,   // [NCOL][K] bf16
    const float* __restrict__ weight,       // [NG][256] fp32
    float* __restrict__ out)                // [32][NG] fp32
{
    // 2 buffers; each: A[256][64] + B[256][64] bf16 (64 KB).  Row = 128 B.
    // LDS slot (r, cp) holds global chunk c = cp ^ (r&7)  [XOR swizzle].
    __shared__ __align__(16) unsigned short lds[2 * 32768];

    const int tid  = threadIdx.x;            // 0..255
    const int lane = tid & 63;
    const int wid  = tid >> 6;               // 0..3
    const int wr   = wid >> 1;               // 0..1  (M half: 128 rows)
    const int wc   = wid & 1;                // 0..1  (N half: 128 cols)
    const int quad = lane >> 4, m = lane & 15;

    const int rowBase = blockIdx.y * 256;    // over NG
    const int colBase = blockIdx.x * 256;    // over NCOL (= b*256)

    // Staging: tile = 2048 chunks of 16B; thread t, round i (0..7):
    // slot s = i*256 + t -> r = i*32 + (t>>3), cp = t&7;
    // global chunk c = cp ^ (r&7) = (t&7) ^ ((t>>3)&7)   [i-invariant].
    const int rS = tid >> 3;
    const int cS = (tid & 7) ^ (rS & 7);
    const unsigned short* pA = G + (size_t)(rowBase + rS) * KDIM + cS * 8;
    const unsigned short* pB = F + (size_t)(colBase + rS) * KDIM + cS * 8;

    // Stage full tile KT (global k0 = KT*64) into buffer at LDS base BUFO.
#define STAGE(BUFO, KT)                                                    \
    {                                                                      \
        const unsigned short* gA = pA + (size_t)(KT) * 64;                 \
        const unsigned short* gB = pB + (size_t)(KT) * 64;                 \
        _Pragma("unroll")                                                  \
        for (int i = 0; i < 8; ++i)                                        \
            async16(gA + i * (32 * KDIM), &lds[(BUFO) + i * 2048 + tid * 8]); \
        _Pragma("unroll")                                                  \
        for (int i = 0; i < 8; ++i)                                        \
            async16(gB + i * (32 * KDIM), &lds[(BUFO) + 16384 + i * 2048 + tid * 8]); \
    }

    // ds_read: row = band + m (band mult of 16), chunk = kk*4+quad, swz ^(m&7)
    const int cs0  = ((quad)     ^ (m & 7)) * 8;   // kk=0
    const int cs1  = ((4 + quad) ^ (m & 7)) * 8;   // kk=1
    const int arow = (wr * 128 + m) * 64;
    const int brow = (wc * 128 + m) * 64;

    f32x4 acc[8][8];
#pragma unroll
    for (int i = 0; i < 8; ++i)
#pragma unroll
        for (int j = 0; j < 8; ++j)
            acc[i][j] = (f32x4){0.f, 0.f, 0.f, 0.f};

    // Prologue: stage tile 0 into buf0, drain, publish.
    STAGE(0, 0);
    asm volatile("s_waitcnt vmcnt(0)" ::: "memory");
    __builtin_amdgcn_s_barrier();
    asm volatile("" ::: "memory");

    // Main loop: tile t from buf t&1; stage t+1 (clamped: last iteration
    // redundantly re-stages tile 35 — same data, drained before epilogue)
    // into the other buffer, issued FIRST for maximum lead time.
    for (int tt = 0; tt < NKT; tt += 2) {
#pragma unroll
        for (int u = 0; u < 2; ++u) {
            const int t   = tt + u;
            const int bo  = u * 32768;           // static
            const int wbo = (u ^ 1) * 32768;     // static
            int w = t + 1; if (w >= NKT) w = NKT - 1;

            STAGE(wbo, w);

            bf16x8 a[8], b[8];
            // ---- kk = 0 ----
#pragma unroll
            for (int i = 0; i < 8; ++i)
                a[i] = *(const bf16x8*)&lds[bo + arow + i * 1024 + cs0];
#pragma unroll
            for (int j = 0; j < 8; ++j)
                b[j] = *(const bf16x8*)&lds[bo + 16384 + brow + j * 1024 + cs0];
            __builtin_amdgcn_s_setprio(1);
#pragma unroll
            for (int i = 0; i < 8; ++i)
#pragma unroll
                for (int j = 0; j < 8; ++j)
                    acc[i][j] = __builtin_amdgcn_mfma_f32_16x16x32_bf16(a[i], b[j], acc[i][j], 0, 0, 0);
            __builtin_amdgcn_s_setprio(0);
            // ---- kk = 1 ----
#pragma unroll
            for (int i = 0; i < 8; ++i)
                a[i] = *(const bf16x8*)&lds[bo + arow + i * 1024 + cs1];
#pragma unroll
            for (int j = 0; j < 8; ++j)
                b[j] = *(const bf16x8*)&lds[bo + 16384 + brow + j * 1024 + cs1];
            __builtin_amdgcn_s_setprio(1);
#pragma unroll
            for (int i = 0; i < 8; ++i)
#pragma unroll
                for (int j = 0; j < 8; ++j)
                    acc[i][j] = __builtin_amdgcn_mfma_f32_16x16x32_bf16(a[i], b[j], acc[i][j], 0, 0, 0);
            __builtin_amdgcn_s_setprio(0);

            // Staged loads for t+1 had a full tile of MFMA lead -> cheap drain.
            asm volatile("s_waitcnt vmcnt(0)" ::: "memory");
            __builtin_amdgcn_s_barrier();
            asm volatile("" ::: "memory");
        }
    }

    __syncthreads();

    // Epilogue: out[b][n] = sum_c pooled[n][b*256+c] * weight[n][c].
    // acc[i][j][reg] = pooled[rowBase + wr*128 + i*16 + quad*4 + reg]
    //                        [colBase + wc*128 + j*16 + m]
    float* red = (float*)lds;                // [2 wc][256 n_local]
    const int cwbase = wc * 128 + m;
#pragma unroll
    for (int i = 0; i < 8; ++i) {
#pragma unroll
        for (int reg = 0; reg < 4; ++reg) {
            const int nloc = wr * 128 + i * 16 + quad * 4 + reg;
            const float* wrow = weight + (size_t)(rowBase + nloc) * 256 + cwbase;
            float s = 0.f;
#pragma unroll
            for (int j = 0; j < 8; ++j)
                s += acc[i][j][reg] * wrow[j * 16];
            s += __shfl_xor(s, 1);
            s += __shfl_xor(s, 2);
            s += __shfl_xor(s, 4);
            s += __shfl_xor(s, 8);
            if (m == 0)
                red[wc * 256 + nloc] = s;
        }
    }
    __syncthreads();
    if (tid < 256) {
        const float s = red[tid] + red[256 + tid];
        out[(size_t)blockIdx.x * NG + rowBase + tid] = s;
    }
}

// ---------------------------------------------------------------------------
extern "C" void kernel_launch(void* const* d_in, const int* in_sizes, int n_in,
                              void* d_out, int out_size, void* d_ws, size_t ws_size,
                              hipStream_t stream) {
    const float* feat   = (const float*)d_in[0];
    const float* mu     = (const float*)d_in[1];
    const float* logsx  = (const float*)d_in[2];
    const float* logsy  = (const float*)d_in[3];
    const float* rho    = (const float*)d_in[4];
    const float* weight = (const float*)d_in[5];
    float* out = (float*)d_out;

    unsigned short* Gbuf = (unsigned short*)d_ws;                  // 4096*2304*2 B
    unsigned short* Fbuf = Gbuf + (size_t)NG * P_HW;               // 8192*2304*2 B

    hipLaunchKernelGGL(prep_kernel, dim3(13312), dim3(256), 0, stream,
                       feat, mu, logsx, logsy, rho, Fbuf, Gbuf);

    hipLaunchKernelGGL(gemm_fused, dim3(NCOL / 256, NG / 256), dim3(256), 0, stream,
                       Gbuf, Fbuf, weight, out);
}